// Round 7
// baseline (207.611 us; speedup 1.0000x reference)
//
#include <hip/hip_runtime.h>
#include <hip/hip_bf16.h>

// AFT-Full: B=4, T=2048, DIM=1024, HID=256
// All GEMMs: m97-structure 128x128 tile, BK=32, single-buffer LDS, 4 waves (2x2),
// 4x4 acc (16 MFMA : 8 ds_read_b128 per wave-step), global_load_lds width-16.
//   prep      : xb=bf16(x); ewb=bf16(exp(wbias)); WqkvT interleaved (0..255=Q,
//               256+2h=K_h, 257+2h=V_h); WpT[d][h]=Wp[h][d]; biascat
//   gemm1_qkv : [8192x768] = xb @ WqkvT^T + biascat. Fused epilogue:
//               Q cols -> sgQ f32 = sigmoid(q); KV cols -> shfl-pair ->
//               B2T bf16 rows b*512+2h = exp(K)*V (num), b*512+2h+1 = exp(K) (den)
//   gemm2     : C2[z] = ewb @ B2T^T over K-slice z (split-K, m102 833TF geometry)
//   elt2      : Yt bf16[8192][256] = sgQ * (Σnum)/(Σden)
//   gemm3     : out = Yt @ WpT^T + bp -> f32 [8192][1024]
// Workspace: [0, 16M*n) xb (dead after gemm1) / C2[n] split-K partials, then at
// base=16M*n: ewb 8M | WqkvT 1.5M | WpT 0.5M | biascat 4K | sgQ 8M | B2T 8M | Yt 4M.
// n = 4 if ws allows (98.6MB), else 2 (65MB), else 1 (48.2MB = round-3-proven).

typedef __attribute__((ext_vector_type(8))) short bf16x8;
typedef __attribute__((ext_vector_type(4))) float f32x4;

static __device__ __forceinline__ unsigned short f2b(float f) {
  __hip_bfloat16 h = __float2bfloat16(f);
  return __builtin_bit_cast(unsigned short, h);
}

static __device__ __forceinline__ void gld16(const void* g, const void* l) {
  __builtin_amdgcn_global_load_lds((const __attribute__((address_space(1))) void*)g,
                                   (__attribute__((address_space(3))) void*)l, 16, 0, 0);
}

// m97-structure core: BM=BN=128, BK=32, single-buffer, 16 MFMA : 8 b128 reads.
// A_blk/Bt_blk point at the block's (row0, k0); row strides sA/sB elements.
static __device__ __forceinline__ void core128(
    const unsigned short* __restrict__ A_blk,
    const unsigned short* __restrict__ Bt_blk,
    long sA, long sB, int nk, char* AsB, char* BsB, f32x4 acc[4][4],
    int tid, int wr, int wc, int fr, int fkb)
{
  const int srow = tid >> 2;          // 16B unit u = tid: row=u>>2, kbyte=(u&3)*16
  const int sk   = (tid & 3) * 8;
  const unsigned short* ap0 = A_blk + (long)srow * sA + sk;
  const unsigned short* ap1 = ap0 + 64 * sA;
  const unsigned short* bp0 = Bt_blk + (long)srow * sB + sk;
  const unsigned short* bp1 = bp0 + 64 * sB;
  char* la0 = AsB + tid * 16;
  char* la1 = AsB + 4096 + tid * 16;
  char* lb0 = BsB + tid * 16;
  char* lb1 = BsB + 4096 + tid * 16;

  for (int kt = 0; kt < nk; ++kt) {
    gld16(ap0, la0);
    gld16(ap1, la1);
    gld16(bp0, lb0);
    gld16(bp1, lb1);
    ap0 += 32; ap1 += 32; bp0 += 32; bp1 += 32;
    asm volatile("s_waitcnt vmcnt(0)" ::: "memory");
    __syncthreads();

    bf16x8 av[4], bv[4];
#pragma unroll
    for (int m = 0; m < 4; ++m)
      av[m] = *(const bf16x8*)(AsB + (wr * 64 + m * 16 + fr) * 64 + fkb);
#pragma unroll
    for (int n = 0; n < 4; ++n)
      bv[n] = *(const bf16x8*)(BsB + (wc * 64 + n * 16 + fr) * 64 + fkb);
#pragma unroll
    for (int m = 0; m < 4; ++m)
#pragma unroll
      for (int n = 0; n < 4; ++n)
        acc[m][n] = __builtin_amdgcn_mfma_f32_16x16x32_bf16(av[m], bv[n], acc[m][n], 0, 0, 0);
    __syncthreads();
  }
}

// Generic C = A @ Bt^T (+bias), with split-K via blockIdx.z (slice width Ksub,
// full row strides KA==KB==K, partial written to C + z*M*N).
__global__ __launch_bounds__(256) void gemm_bt(
    const unsigned short* __restrict__ A, const unsigned short* __restrict__ Bt,
    float* __restrict__ C, const float* __restrict__ bias,
    int M, int N, int K, int Ksub)
{
  __shared__ char AsB[8192];
  __shared__ char BsB[8192];
  const int tid = threadIdx.x, lane = tid & 63, wave = tid >> 6;
  const int wr = wave >> 1, wc = wave & 1;
  const int fr = lane & 15, fkb = (lane >> 4) * 16, q4 = (lane >> 4) * 4;
  const long bm = (long)blockIdx.y * 128;
  const long bn = (long)blockIdx.x * 128;
  const long k0 = (long)blockIdx.z * Ksub;

  f32x4 acc[4][4] = {};
  core128(A + bm * K + k0, Bt + bn * K + k0, K, K, Ksub >> 5,
          AsB, BsB, acc, tid, wr, wc, fr, fkb);

  float* Cz = C + (long)blockIdx.z * M * (long)N;
  const long crow0 = bm + wr * 64 + q4;
  const long ccol0 = bn + wc * 64 + fr;
#pragma unroll
  for (int n = 0; n < 4; ++n) {
    const long col = ccol0 + n * 16;
    const float bb = bias ? bias[col] : 0.f;
#pragma unroll
    for (int m = 0; m < 4; ++m)
#pragma unroll
      for (int r = 0; r < 4; ++r)
        Cz[(crow0 + m * 16 + r) * (long)N + col] = acc[m][n][r] + bb;
  }
}

// gemm1: QKV projection with fused sigmoid / exp / transpose epilogue
__global__ __launch_bounds__(256) void gemm1_qkv(
    const unsigned short* __restrict__ xb, const unsigned short* __restrict__ WqkvT,
    const float* __restrict__ biascat,
    float* __restrict__ sgQ, unsigned short* __restrict__ B2T)
{
  __shared__ char AsB[8192];
  __shared__ char BsB[8192];
  const int tid = threadIdx.x, lane = tid & 63, wave = tid >> 6;
  const int wr = wave >> 1, wc = wave & 1;
  const int fr = lane & 15, fkb = (lane >> 4) * 16, q4 = (lane >> 4) * 4;
  const long bm = (long)blockIdx.y * 128;   // row in [0,8192)
  const long bn = (long)blockIdx.x * 128;   // col in [0,768)
  const int  b  = (int)(bm >> 11);
  const int  tb = (int)(bm & 2047);

  f32x4 acc[4][4] = {};
  core128(xb + bm * 1024, WqkvT + bn * 1024, 1024, 1024, 32,
          AsB, BsB, acc, tid, wr, wc, fr, fkb);

  if (bn < 256) {
    // Q: sigmoid -> sgQ f32 [8192][256]
#pragma unroll
    for (int n = 0; n < 4; ++n) {
      const int col = (int)bn + wc * 64 + n * 16 + fr;
      const float bb = biascat[col];
#pragma unroll
      for (int m = 0; m < 4; ++m)
#pragma unroll
        for (int r = 0; r < 4; ++r) {
          long row = bm + wr * 64 + m * 16 + q4 + r;
          float v = acc[m][n][r] + bb;
          sgQ[row * 256 + col] = 1.f / (1.f + __expf(-v));
        }
    }
  } else {
    // KV: pair K (even u) with V (odd u) via shfl_xor(1); B2T rows interleaved
#pragma unroll
    for (int n = 0; n < 4; ++n) {
      const int col = (int)bn + wc * 64 + n * 16 + fr;
      const int u   = col - 256;
      const float bb = biascat[col];
      const bool isK = (u & 1) == 0;
      const long rw = (long)b * 512 + u + (isK ? 1 : -1);
#pragma unroll
      for (int m = 0; m < 4; ++m) {
        float v[4], o[4];
#pragma unroll
        for (int r = 0; r < 4; ++r) v[r] = acc[m][n][r] + bb;
#pragma unroll
        for (int r = 0; r < 4; ++r) o[r] = __shfl_xor(v[r], 1);
        ushort4 pk;
        if (isK) {       // den row: exp(K)
          pk.x = f2b(__expf(v[0])); pk.y = f2b(__expf(v[1]));
          pk.z = f2b(__expf(v[2])); pk.w = f2b(__expf(v[3]));
        } else {         // num row: exp(K)*V
          pk.x = f2b(__expf(o[0]) * v[0]); pk.y = f2b(__expf(o[1]) * v[1]);
          pk.z = f2b(__expf(o[2]) * v[2]); pk.w = f2b(__expf(o[3]) * v[3]);
        }
        const int t0 = tb + wr * 64 + m * 16 + q4;
        *(ushort4*)(B2T + rw * 2048 + t0) = pk;
      }
    }
  }
}

// elt2: Yt[m][h] = bf16( sgQ[m][h] * Σz num / Σz den )
__global__ void elt2_kernel(const float* __restrict__ C2, const float* __restrict__ sgQ,
                            unsigned short* __restrict__ Yt, int nslices) {
  int idx = blockIdx.x * 256 + threadIdx.x;   // 8192*256
  int h = idx & 255, m = idx >> 8;
  int b = m >> 11, tt = m & 2047;
  long p2 = ((long)tt * 2048 + b * 512) >> 1;  // float2 index of (num,den) pair 0
  const float2* C22 = (const float2*)C2;
  float num = 0.f, den = 0.f;
  for (int z = 0; z < nslices; ++z) {
    float2 nd = C22[(long)z * 2097152 + p2 + h];
    num += nd.x; den += nd.y;
  }
  Yt[idx] = f2b(sgQ[idx] * num / den);
}

// prep: converts + weight transposes
__global__ void prep_kernel(const float* __restrict__ x, const float* __restrict__ wbias,
                            const float* __restrict__ Wq, const float* __restrict__ Wk,
                            const float* __restrict__ Wv, const float* __restrict__ bq,
                            const float* __restrict__ bk, const float* __restrict__ bv,
                            const float* __restrict__ Wp,
                            unsigned short* __restrict__ xb, unsigned short* __restrict__ ewb,
                            unsigned short* __restrict__ WqkvT, unsigned short* __restrict__ WpT,
                            float* __restrict__ biascat) {
  const int bid = blockIdx.x;
  const int t = threadIdx.x;
  if (bid < 8192) {
    int i = bid * 256 + t;
    float4 v = ((const float4*)x)[i];
    ushort4 o; o.x = f2b(v.x); o.y = f2b(v.y); o.z = f2b(v.z); o.w = f2b(v.w);
    ((ushort4*)xb)[i] = o;
  } else if (bid < 12288) {
    int i = (bid - 8192) * 256 + t;
    float4 v = ((const float4*)wbias)[i];
    ushort4 o;
    o.x = f2b(__expf(v.x)); o.y = f2b(__expf(v.y));
    o.z = f2b(__expf(v.z)); o.w = f2b(__expf(v.w));
    ((ushort4*)ewb)[i] = o;
  } else {
    int idx = (bid - 12288) * 256 + t;
    if (idx < 768 * 1024) {              // cols: n<256 Q_n; 256+2h K_h; 257+2h V_h
      int n = idx >> 10, k = idx & 1023;
      const float* W; int c;
      if (n < 256) { W = Wq; c = n; }
      else { int u = n - 256; c = u >> 1; W = (u & 1) ? Wv : Wk; }
      WqkvT[idx] = f2b(W[k * 256 + c]);
    }
    if (idx < 1024 * 256) {              // WpT[d][h] = Wp[h][d]
      int d = idx >> 8, h = idx & 255;
      WpT[idx] = f2b(Wp[h * 1024 + d]);
    }
    if (idx < 768) {
      float v;
      if (idx < 256) v = bq[idx];
      else { int u = idx - 256; v = (u & 1) ? bv[u >> 1] : bk[u >> 1]; }
      biascat[idx] = v;
    }
  }
}

extern "C" void kernel_launch(void* const* d_in, const int* in_sizes, int n_in,
                              void* d_out, int out_size, void* d_ws, size_t ws_size,
                              hipStream_t stream) {
  const float* x     = (const float*)d_in[0];
  const float* Wq    = (const float*)d_in[1];
  const float* bq    = (const float*)d_in[2];
  const float* Wk    = (const float*)d_in[3];
  const float* bk    = (const float*)d_in[4];
  const float* Wv    = (const float*)d_in[5];
  const float* bv    = (const float*)d_in[6];
  const float* Wp    = (const float*)d_in[7];
  const float* bp    = (const float*)d_in[8];
  const float* wbias = (const float*)d_in[9];

  // split-K slices bounded by workspace: need n*16M (C2) + 30.0M (rest)
  int nslices = 1;
  if (ws_size >= 4ull * 16777216 + 31461376) nslices = 4;
  else if (ws_size >= 2ull * 16777216 + 31461376) nslices = 2;

  char* ws = (char*)d_ws;
  const long base = (long)nslices * 16777216;
  unsigned short* xb      = (unsigned short*)(ws + 0);           // dead after gemm1
  float*          C2      = (float*)(ws + 0);                    // nslices x 16MB
  unsigned short* ewb     = (unsigned short*)(ws + base);        // 8 MB
  unsigned short* WqkvT   = (unsigned short*)(ws + base + 8388608);
  unsigned short* WpT     = (unsigned short*)(ws + base + 9961472);
  float*          biascat = (float*)(ws + base + 10485760);
  float*          sgQ     = (float*)(ws + base + 10489856);      // 8 MB
  unsigned short* B2T     = (unsigned short*)(ws + base + 18878464); // 8 MB
  unsigned short* Yt      = (unsigned short*)(ws + base + 27267072); // 4 MB
  float* out = (float*)d_out;

  prep_kernel<<<15360, 256, 0, stream>>>(x, wbias, Wq, Wk, Wv, bq, bk, bv, Wp,
                                         xb, ewb, WqkvT, WpT, biascat);
  gemm1_qkv<<<dim3(6, 64), 256, 0, stream>>>(xb, WqkvT, biascat, sgQ, B2T);
  gemm_bt<<<dim3(16, 16, nslices), 256, 0, stream>>>(ewb, B2T, C2, nullptr,
                                                     2048, 2048, 2048, 2048 / nslices);
  elt2_kernel<<<8192, 256, 0, stream>>>(C2, sgQ, Yt, nslices);
  gemm_bt<<<dim3(8, 64, 1), 256, 0, stream>>>(Yt, WpT, out, bp, 8192, 1024, 256, 256);
}